// Round 6
// baseline (1178.344 us; speedup 1.0000x reference)
//
#include <hip/hip_runtime.h>
#include <math.h>

// ---------------------------------------------------------------------------
// NystromAttention round 6: pinv as barrier-free MFMA on pre-split bf16 hi/lo
// operand pairs; attn3_flash kc=8 for occupancy.
// b=4 n=4096 dim=512 h=8 d=64 m=256, l=16, iters=6, conv k=33.
// MFMA 16x16x32_bf16 layouts (HW-verified per guide):
//   A: m=lane&15, k=(lane>>4)*8+j    B: n=lane&15, k=(lane>>4)*8+j
//   C/D: col=lane&15, row=(lane>>4)*4+reg
// ---------------------------------------------------------------------------

#define QKV_STRIDE 262144   // 4096*64 per (b,h)
#define LM_STRIDE 16384     // 256*64
#define MM_STRIDE 65536     // 256*256

typedef float f32x4 __attribute__((ext_vector_type(4)));
typedef short bf8 __attribute__((ext_vector_type(8)));   // 8 bf16 in 4 VGPRs
typedef short s4v __attribute__((ext_vector_type(4)));

__device__ __forceinline__ unsigned short f2bf_(float f) {
  unsigned u = __float_as_uint(f);
  u += 0x7FFFu + ((u >> 16) & 1u);   // RNE
  return (unsigned short)(u >> 16);
}
__device__ __forceinline__ float bf2f_(unsigned short h) {
  return __uint_as_float(((unsigned)h) << 16);
}
__device__ __forceinline__ bf8 pack8(const float4 a, const float4 b) {
  bf8 r;
  r[0] = (short)f2bf_(a.x); r[1] = (short)f2bf_(a.y);
  r[2] = (short)f2bf_(a.z); r[3] = (short)f2bf_(a.w);
  r[4] = (short)f2bf_(b.x); r[5] = (short)f2bf_(b.y);
  r[6] = (short)f2bf_(b.z); r[7] = (short)f2bf_(b.w);
  return r;
}

__global__ __launch_bounds__(256) void zero_scal(float* scal) {
  if (threadIdx.x < 2) scal[threadIdx.x] = 0.0f;
}

// ------------- transpose + fp32->bf16: dst[C][R] = bf16(src[R][C]) ----------
__global__ __launch_bounds__(256) void transpose_bf16(const float* __restrict__ src,
                                                      short* __restrict__ dst,
                                                      int R, int C) {
  __shared__ float T[32][33];
  const int t = threadIdx.x;
  const int c0 = blockIdx.x * 32, r0 = blockIdx.y * 32;
  const int tr = t >> 3, tc = (t & 7) << 2;
  float4 vsrc = *(const float4*)&src[(size_t)(r0 + tr) * C + c0 + tc];
  T[tr][tc + 0] = vsrc.x; T[tr][tc + 1] = vsrc.y;
  T[tr][tc + 2] = vsrc.z; T[tr][tc + 3] = vsrc.w;
  __syncthreads();
  s4v o;
  o[0] = (short)f2bf_(T[tc + 0][tr]);
  o[1] = (short)f2bf_(T[tc + 1][tr]);
  o[2] = (short)f2bf_(T[tc + 2][tr]);
  o[3] = (short)f2bf_(T[tc + 3][tr]);
  *(s4v*)&dst[(size_t)(c0 + tr) * R + r0 + tc] = o;
}

// ---- qkv = x @ w_qkv via MFMA -> qb16/kb16 row-major bf16, vT16 bf16 -------
__global__ __launch_bounds__(256) void gemm_qkv_mfma(const float* __restrict__ x,
                                                     const short* __restrict__ wT,
                                                     short* __restrict__ qb16,
                                                     short* __restrict__ kb16,
                                                     short* __restrict__ vT16) {
  __shared__ short SMEM[17408];   // As[0..4095], Bs[4096..8191]; v: stage 128x136
  short* As = SMEM;
  short* Bs = SMEM + 4096;
  const int tid = threadIdx.x;
  const int lane = tid & 63, w = tid >> 6;
  const int wr = w >> 1, wc = w & 1;
  const int gm0 = blockIdx.x * 128, gn0 = blockIdx.y * 128;
  const int mA0 = (tid >> 6) * 16 + (tid & 15), kA0 = ((tid >> 4) & 3) * 8;
  const int s1 = tid + 256;
  const int mA1 = (s1 >> 6) * 16 + (s1 & 15), kA1 = ((s1 >> 4) & 3) * 8;
  f32x4 acc[4][4];
#pragma unroll
  for (int i = 0; i < 4; ++i)
#pragma unroll
    for (int j = 0; j < 4; ++j) acc[i][j] = (f32x4){0.f, 0.f, 0.f, 0.f};
  for (int kt = 0; kt < 16; ++kt) {
    const int k0 = kt * 32;
    float4 a0 = *(const float4*)&x[(size_t)(gm0 + mA0) * 512 + k0 + kA0];
    float4 a1 = *(const float4*)&x[(size_t)(gm0 + mA0) * 512 + k0 + kA0 + 4];
    float4 a2 = *(const float4*)&x[(size_t)(gm0 + mA1) * 512 + k0 + kA1];
    float4 a3 = *(const float4*)&x[(size_t)(gm0 + mA1) * 512 + k0 + kA1 + 4];
    bf8 b0 = *(const bf8*)&wT[(size_t)(gn0 + mA0) * 512 + k0 + kA0];
    bf8 b1 = *(const bf8*)&wT[(size_t)(gn0 + mA1) * 512 + k0 + kA1];
    __syncthreads();
    *(bf8*)&As[tid * 8] = pack8(a0, a1);
    *(bf8*)&As[s1 * 8] = pack8(a2, a3);
    *(bf8*)&Bs[tid * 8] = b0;
    *(bf8*)&Bs[s1 * 8] = b1;
    __syncthreads();
    bf8 af[4], bf[4];
#pragma unroll
    for (int i = 0; i < 4; ++i) {
      af[i] = *(const bf8*)&As[((wr * 4 + i) * 64 + lane) * 8];
      bf[i] = *(const bf8*)&Bs[((wc * 4 + i) * 64 + lane) * 8];
    }
#pragma unroll
    for (int i = 0; i < 4; ++i)
#pragma unroll
      for (int j = 0; j < 4; ++j)
        acc[i][j] = __builtin_amdgcn_mfma_f32_16x16x32_bf16(af[i], bf[j], acc[i][j], 0, 0, 0);
  }
  const int which = blockIdx.y >> 2;  // 0:q 1:k 2:v
  const int qd = lane >> 4, c = lane & 15;
  if (which < 2) {
    short* dst = which == 0 ? qb16 : kb16;
    const float scale = which == 0 ? 0.125f : 1.0f;
#pragma unroll
    for (int i = 0; i < 4; ++i)
#pragma unroll
      for (int j = 0; j < 4; ++j) {
        const int col = gn0 + wc * 64 + j * 16 + c;
        const int head = (col >> 6) & 7, dd = col & 63;
#pragma unroll
        for (int r = 0; r < 4; ++r) {
          const int row = gm0 + wr * 64 + i * 16 + qd * 4 + r;
          const int b = row >> 12, seq = row & 4095;
          dst[(size_t)(b * 8 + head) * QKV_STRIDE + seq * 64 + dd] =
              (short)f2bf_(acc[i][j][r] * scale);
        }
      }
  } else {
    __syncthreads();
#pragma unroll
    for (int i = 0; i < 4; ++i)
#pragma unroll
      for (int j = 0; j < 4; ++j) {
        const int colL = wc * 64 + j * 16 + c;
#pragma unroll
        for (int r = 0; r < 4; ++r) {
          const int rowL = wr * 64 + i * 16 + qd * 4 + r;
          SMEM[colL * 136 + rowL] = (short)f2bf_(acc[i][j][r]);
        }
      }
    __syncthreads();
    const int b = gm0 >> 12, seq0 = gm0 & 4095;
    const int dcol = tid >> 1, half = tid & 1;
    const int col = gn0 + dcol;
    const int head = (col >> 6) & 7, d = col & 63;
    const short* src = &SMEM[dcol * 136 + half * 64];
    short* dstp = &vT16[(size_t)(b * 8 + head) * QKV_STRIDE + (size_t)d * 4096 +
                        seq0 + half * 64];
#pragma unroll
    for (int u = 0; u < 16; ++u) *(s4v*)&dstp[u * 4] = *(const s4v*)&src[u * 4];
  }
}

// ---------------- landmark means (bf16 in, fp32 + bf16-kl out) --------------
__global__ __launch_bounds__(256) void lmk_mean(const short* __restrict__ qb16,
                                                const short* __restrict__ kb16,
                                                float* __restrict__ ql,
                                                float* __restrict__ kl,
                                                short* __restrict__ klb16) {
  const int g = blockIdx.x * 256 + threadIdx.x;
  const int dd = g & 63, mi = (g >> 6) & 255, bh = g >> 14;
  const size_t base = (size_t)bh * QKV_STRIDE + mi * 1024 + dd;
  float sq = 0.f, sk = 0.f;
#pragma unroll
  for (int jj = 0; jj < 16; ++jj) {
    sq += bf2f_((unsigned short)qb16[base + jj * 64]);
    sk += bf2f_((unsigned short)kb16[base + jj * 64]);
  }
  const float qv = sq * 0.0625f, kv = sk * 0.0625f;
  ql[g] = qv;
  kl[g] = kv;
  klb16[g] = (short)f2bf_(kv);
}

// ---------------- sim2 = ql @ kl^T, softmax -> x2 ---------------------------
__global__ __launch_bounds__(256) void sim2_softmax(const float* __restrict__ ql,
                                                    const float* __restrict__ kl,
                                                    float* __restrict__ x2) {
  const int blk = blockIdx.x;
  const int bh = blk >> 4, rg = blk & 15;
  __shared__ float Qs[16][64];
  __shared__ float Ks[64][68];
  __shared__ float S[16][257];
  __shared__ float red[16][17];
  __shared__ float rowinv[16];
  const int tid = threadIdx.x;
  const int r = tid >> 4, jc = tid & 15;
#pragma unroll
  for (int u = 0; u < 4; ++u) {
    int t2 = tid + u * 256;
    Qs[t2 >> 6][t2 & 63] =
        ql[(size_t)bh * LM_STRIDE + (rg * 16 + (t2 >> 6)) * 64 + (t2 & 63)];
  }
  for (int c = 0; c < 4; ++c) {
    __syncthreads();
#pragma unroll
    for (int u = 0; u < 4; ++u) {
      int t4 = tid + u * 256;
      int row = t4 >> 4, c4 = (t4 & 15) << 2;
      *(float4*)&Ks[row][c4] =
          *(const float4*)&kl[(size_t)bh * LM_STRIDE + (c * 64 + row) * 64 + c4];
    }
    __syncthreads();
#pragma unroll
    for (int s = 0; s < 4; ++s) {
      const int jj = jc + (s << 4);
      float acc = 0.f;
#pragma unroll
      for (int k4 = 0; k4 < 16; ++k4) {
        const float4 a = *(const float4*)&Qs[r][k4 << 2];
        const float4 bb = *(const float4*)&Ks[jj][k4 << 2];
        acc += a.x * bb.x + a.y * bb.y + a.z * bb.z + a.w * bb.w;
      }
      S[r][(c << 6) + jj] = acc;
    }
  }
  __syncthreads();
  float pm = -3.0e38f;
#pragma unroll
  for (int u = 0; u < 16; ++u) pm = fmaxf(pm, S[r][jc + (u << 4)]);
  red[r][jc] = pm;
  __syncthreads();
  float m = red[r][0];
#pragma unroll
  for (int u = 1; u < 16; ++u) m = fmaxf(m, red[r][u]);
  __syncthreads();
  float ps = 0.f;
#pragma unroll
  for (int u = 0; u < 16; ++u) {
    const int j = jc + (u << 4);
    const float e = __expf(S[r][j] - m);
    S[r][j] = e;
    ps += e;
  }
  red[r][jc] = ps;
  __syncthreads();
  if (jc == 0) {
    float sum = 0.f;
#pragma unroll
    for (int u = 0; u < 16; ++u) sum += red[r][u];
    rowinv[r] = 1.0f / sum;
  }
  __syncthreads();
  for (int idx = tid; idx < 4096; idx += 256) {
    const int rr = idx >> 8, j = idx & 255;
    x2[(size_t)bh * MM_STRIDE + (rg * 16 + rr) * 256 + j] = S[rr][j] * rowinv[rr];
  }
}

// ---------------- global max of col/row abs-sums ----------------------------
__global__ __launch_bounds__(256) void colrow_max(const float* __restrict__ x2,
                                                  float* __restrict__ scal) {
  const int bh = blockIdx.x;
  const int tid = threadIdx.x;
  const float* xb = x2 + (size_t)bh * MM_STRIDE;
  float cs = 0.f, rs = 0.f;
  for (int j = 0; j < 256; ++j) cs += fabsf(xb[tid * 256 + j]);
  for (int i = 0; i < 256; ++i) rs += fabsf(xb[i * 256 + tid]);
  __shared__ float rc[256], rr[256];
  rc[tid] = cs; rr[tid] = rs;
  __syncthreads();
  for (int st = 128; st > 0; st >>= 1) {
    if (tid < st) {
      rc[tid] = fmaxf(rc[tid], rc[tid + st]);
      rr[tid] = fmaxf(rr[tid], rr[tid + st]);
    }
    __syncthreads();
  }
  if (tid == 0) {
    atomicMax((int*)&scal[0], __float_as_int(rc[0]));
    atomicMax((int*)&scal[1], __float_as_int(rr[0]));
  }
}

// --------- x2 -> hi/lo bf16 pair (row-major) --------------------------------
__global__ __launch_bounds__(256) void x2split(const float* __restrict__ x2,
                                               short* __restrict__ x2h,
                                               short* __restrict__ x2l) {
  const int g = blockIdx.x * 256 + threadIdx.x;
  const float v = x2[g];
  const unsigned short h = f2bf_(v);
  x2h[g] = (short)h;
  x2l[g] = (short)f2bf_(v - bf2f_(h));
}

// --------- z0 = x2^T/s, z0t = x2/s, both as bf16 hi/lo pairs ----------------
__global__ __launch_bounds__(256) void tscale_split(const float* __restrict__ x2,
                                                    const float* __restrict__ scal,
                                                    short* __restrict__ zh,
                                                    short* __restrict__ zl,
                                                    short* __restrict__ zth,
                                                    short* __restrict__ ztl) {
  __shared__ float T[64][68];
  const int bh = blockIdx.x >> 4, tile = blockIdx.x & 15;
  const int ti = tile >> 2, tj = tile & 3;
  const int tid = threadIdx.x;
  const float inv = 1.0f / (scal[0] * scal[1]);
  const int r = tid >> 2, cc = (tid & 3) * 16;
  float v[16];
#pragma unroll
  for (int u = 0; u < 4; ++u) {
    float4 x4 = *(const float4*)&x2[(size_t)bh * MM_STRIDE + (ti * 64 + r) * 256 +
                                    tj * 64 + cc + u * 4];
    v[u * 4 + 0] = x4.x * inv; v[u * 4 + 1] = x4.y * inv;
    v[u * 4 + 2] = x4.z * inv; v[u * 4 + 3] = x4.w * inv;
  }
#pragma unroll
  for (int e = 0; e < 16; ++e) T[r][cc + e] = v[e];
  // zt rows (= x2/s): coalesced
  {
    const size_t gi = (size_t)bh * MM_STRIDE + (ti * 64 + r) * 256 + tj * 64 + cc;
    bf8 hi0, lo0, hi1, lo1;
#pragma unroll
    for (int e = 0; e < 8; ++e) {
      unsigned short h0 = f2bf_(v[e]);
      hi0[e] = (short)h0; lo0[e] = (short)f2bf_(v[e] - bf2f_(h0));
      unsigned short h1 = f2bf_(v[8 + e]);
      hi1[e] = (short)h1; lo1[e] = (short)f2bf_(v[8 + e] - bf2f_(h1));
    }
    *(bf8*)&zth[gi] = hi0; *(bf8*)&zth[gi + 8] = hi1;
    *(bf8*)&ztl[gi] = lo0; *(bf8*)&ztl[gi + 8] = lo1;
  }
  __syncthreads();
  // z rows (= x2^T/s): from transposed LDS
  {
    const int rr = tid >> 2, cc2 = (tid & 3) * 16;
    float t[16];
#pragma unroll
    for (int e = 0; e < 16; ++e) t[e] = T[cc2 + e][rr];
    const size_t gi = (size_t)bh * MM_STRIDE + (tj * 64 + rr) * 256 + ti * 64 + cc2;
    bf8 hi0, lo0, hi1, lo1;
#pragma unroll
    for (int e = 0; e < 8; ++e) {
      unsigned short h0 = f2bf_(t[e]);
      hi0[e] = (short)h0; lo0[e] = (short)f2bf_(t[e] - bf2f_(h0));
      unsigned short h1 = f2bf_(t[8 + e]);
      hi1[e] = (short)h1; lo1[e] = (short)f2bf_(t[8 + e] - bf2f_(h1));
    }
    *(bf8*)&zh[gi] = hi0; *(bf8*)&zh[gi + 8] = hi1;
    *(bf8*)&zl[gi] = lo0; *(bf8*)&zl[gi + 8] = lo1;
  }
}

// --------- pinv product on pre-split bf16 pairs: C = alpha*E + beta*(A@B) ---
// A row-major pair, BT (=B^T) row-major pair, E row-major pair.
// Barrier-free K-loop (direct global frag loads). Tile 64m x 32n, grid 1024.
__global__ __launch_bounds__(256) void pinv_mfma(const short* __restrict__ Ah,
                                                 const short* __restrict__ Al,
                                                 const short* __restrict__ BTh,
                                                 const short* __restrict__ BTl,
                                                 const short* __restrict__ Eh,
                                                 const short* __restrict__ El,
                                                 short* __restrict__ Ch,
                                                 short* __restrict__ Cl,
                                                 short* __restrict__ CTh,
                                                 short* __restrict__ CTl,
                                                 float alpha, float beta,
                                                 int wantC, int wantT) {
  __shared__ float Tbuf[32 * 68];
  const int tid = threadIdx.x;
  const int lane = tid & 63, w = tid >> 6;
  const int qd = lane >> 4, c = lane & 15;
  // swizzle: all 32 tiles of a batch land on one XCD
  const int bid = blockIdx.x;
  const int xcd = bid & 7, y = bid >> 3;
  const int t32 = y & 31, bgrp = y >> 5;
  const int batch = bgrp * 8 + xcd;
  const int tm = t32 >> 3, tn = t32 & 7;
  const size_t base = (size_t)batch * MM_STRIDE;
  const int m = tm * 64 + w * 16 + c;
  f32x4 acc[2];
  acc[0] = (f32x4){0.f, 0.f, 0.f, 0.f};
  acc[1] = (f32x4){0.f, 0.f, 0.f, 0.f};
  for (int kt = 0; kt < 8; ++kt) {
    const int k0 = kt * 32 + qd * 8;
    bf8 ah = *(const bf8*)&Ah[base + (size_t)m * 256 + k0];
    bf8 al = *(const bf8*)&Al[base + (size_t)m * 256 + k0];
#pragma unroll
    for (int j = 0; j < 2; ++j) {
      const int n = tn * 32 + j * 16 + c;
      bf8 bh = *(const bf8*)&BTh[base + (size_t)n * 256 + k0];
      bf8 bl = *(const bf8*)&BTl[base + (size_t)n * 256 + k0];
      acc[j] = __builtin_amdgcn_mfma_f32_16x16x32_bf16(ah, bh, acc[j], 0, 0, 0);
      acc[j] = __builtin_amdgcn_mfma_f32_16x16x32_bf16(ah, bl, acc[j], 0, 0, 0);
      acc[j] = __builtin_amdgcn_mfma_f32_16x16x32_bf16(al, bh, acc[j], 0, 0, 0);
    }
  }
  float vals[2][4];
#pragma unroll
  for (int j = 0; j < 2; ++j) {
    const int col = tn * 32 + j * 16 + c;
#pragma unroll
    for (int r = 0; r < 4; ++r) {
      const int row = tm * 64 + w * 16 + qd * 4 + r;
      float e = 0.f;
      if (alpha != 0.0f)
        e = alpha * (bf2f_((unsigned short)Eh[base + (size_t)row * 256 + col]) +
                     bf2f_((unsigned short)El[base + (size_t)row * 256 + col]));
      const float val = e + beta * acc[j][r];
      vals[j][r] = val;
      if (wantC) {
        const unsigned short h = f2bf_(val);
        Ch[base + (size_t)row * 256 + col] = (short)h;
        Cl[base + (size_t)row * 256 + col] = (short)f2bf_(val - bf2f_(h));
      }
    }
  }
  if (wantT) {
#pragma unroll
    for (int j = 0; j < 2; ++j)
#pragma unroll
      for (int r = 0; r < 4; ++r)
        Tbuf[(j * 16 + c) * 68 + w * 16 + qd * 4 + r] = vals[j][r];
    __syncthreads();
    const int ctr = tid >> 3, off = (tid & 7) * 8;
    float t[8];
#pragma unroll
    for (int e = 0; e < 8; ++e) t[e] = Tbuf[ctr * 68 + off + e];
    bf8 hi, lo;
#pragma unroll
    for (int e = 0; e < 8; ++e) {
      unsigned short h = f2bf_(t[e]);
      hi[e] = (short)h;
      lo[e] = (short)f2bf_(t[e] - bf2f_(h));
    }
    const size_t gi = base + (size_t)(tn * 32 + ctr) * 256 + tm * 64 + off;
    *(bf8*)&CTh[gi] = hi;
    *(bf8*)&CTl[gi] = lo;
  }
}

// ---- attn3 flash: O_part = exp(ql@k^T - m) @ v over a 512-key chunk --------
__global__ __launch_bounds__(256) void attn3_flash(const float* __restrict__ ql,
                                                   const short* __restrict__ kb16,
                                                   const short* __restrict__ vT16,
                                                   float* __restrict__ opart,
                                                   float* __restrict__ mpart,
                                                   float* __restrict__ lpart) {
  const int kc = blockIdx.x;   // key chunk 0..7 (512 keys each)
  const int rt = blockIdx.y;   // row tile 0..3 (64 rows each)
  const int bh = blockIdx.z;   // 0..31
  __shared__ short Pa[16384];  // 64 rows x 256 keys, A-frag order
  __shared__ float redM[4][64], redS[4][64];
  __shared__ float mRow[64], lRow[64], alphaRow[64];
  const int tid = threadIdx.x, lane = tid & 63, w = tid >> 6;
  const int qd = lane >> 4, c = lane & 15;
  const int r0 = rt * 64;
  const float* qlp = ql + (size_t)bh * LM_STRIDE;
  const short* kp = kb16 + (size_t)bh * QKV_STRIDE;
  const short* vp = vT16 + (size_t)bh * QKV_STRIDE;
  bf8 af[2][4];
#pragma unroll
  for (int st = 0; st < 2; ++st)
#pragma unroll
    for (int i = 0; i < 4; ++i) {
      float4 x0 = *(const float4*)&qlp[(size_t)(r0 + i * 16 + c) * 64 + st * 32 + qd * 8];
      float4 x1 = *(const float4*)&qlp[(size_t)(r0 + i * 16 + c) * 64 + st * 32 + qd * 8 + 4];
      af[st][i] = pack8(x0, x1);
    }
  if (tid < 64) { mRow[tid] = -3.0e38f; lRow[tid] = 0.f; }
  f32x4 accO[4];
#pragma unroll
  for (int nb = 0; nb < 4; ++nb) accO[nb] = (f32x4){0.f, 0.f, 0.f, 0.f};
  __syncthreads();
  for (int it = 0; it < 2; ++it) {
    const int kb0 = kc * 512 + it * 256;
    f32x4 acc[4][4];
#pragma unroll
    for (int i = 0; i < 4; ++i)
#pragma unroll
      for (int j = 0; j < 4; ++j) acc[i][j] = (f32x4){0.f, 0.f, 0.f, 0.f};
#pragma unroll
    for (int st = 0; st < 2; ++st) {
      bf8 bfk[4];
#pragma unroll
      for (int j = 0; j < 4; ++j)
        bfk[j] = *(const bf8*)&kp[(size_t)(kb0 + w * 64 + j * 16 + c) * 64 + st * 32 + qd * 8];
#pragma unroll
      for (int i = 0; i < 4; ++i)
#pragma unroll
        for (int j = 0; j < 4; ++j)
          acc[i][j] = __builtin_amdgcn_mfma_f32_16x16x32_bf16(af[st][i], bfk[j], acc[i][j], 0, 0, 0);
    }
#pragma unroll
    for (int i = 0; i < 4; ++i)
#pragma unroll
      for (int r = 0; r < 4; ++r) {
        float m0 = fmaxf(fmaxf(acc[i][0][r], acc[i][1][r]),
                         fmaxf(acc[i][2][r], acc[i][3][r]));
        m0 = fmaxf(m0, __shfl_xor(m0, 1));
        m0 = fmaxf(m0, __shfl_xor(m0, 2));
        m0 = fmaxf(m0, __shfl_xor(m0, 4));
        m0 = fmaxf(m0, __shfl_xor(m0, 8));
        if (c == 0) redM[w][i * 16 + qd * 4 + r] = m0;
      }
    __syncthreads();
    if (tid < 64) {
      float mN = fmaxf(fmaxf(redM[0][tid], redM[1][tid]),
                       fmaxf(redM[2][tid], redM[3][tid]));
      mN = fmaxf(mN, mRow[tid]);
      const float a = __expf(mRow[tid] - mN);
      alphaRow[tid] = a;
      mRow[tid] = mN;
      lRow[tid] *= a;
    }
    __syncthreads();
#pragma unroll
    for (int r = 0; r < 4; ++r) {
      const float a = alphaRow[w * 16 + qd * 4 + r];
#pragma unroll
      for (int nb = 0; nb < 4; ++nb) accO[nb][r] *= a;
    }
#pragma unroll
    for (int i = 0; i < 4; ++i)
#pragma unroll
      for (int r = 0; r < 4; ++r) {
        const int row = i * 16 + qd * 4 + r;
        const float mrow = mRow[row];
        float s = 0.f;
#pragma unroll
        for (int j = 0; j < 4; ++j) {
          const float e = __expf(acc[i][j][r] - mrow);
          acc[i][j][r] = e;
          s += e;
        }
        s += __shfl_xor(s, 1);
        s += __shfl_xor(s, 2);
        s += __shfl_xor(s, 4);
        s += __shfl_xor(s, 8);
        if (c == 0) redS[w][row] = s;
      }
    __syncthreads();
    if (tid < 64)
      lRow[tid] += redS[0][tid] + redS[1][tid] + redS[2][tid] + redS[3][tid];
#pragma unroll
    for (int i = 0; i < 4; ++i)
#pragma unroll
      for (int r = 0; r < 4; ++r) {
        const int row = i * 16 + qd * 4 + r;
#pragma unroll
        for (int j = 0; j < 4; ++j) {
          const int col = w * 64 + j * 16 + c;
          const int kbk = col >> 5;
          const int lane2 = (row & 15) + 16 * ((col >> 3) & 3);
          Pa[((kbk * 4 + i) * 64 + lane2) * 8 + (col & 7)] = (short)f2bf_(acc[i][j][r]);
        }
      }
    __syncthreads();
#pragma unroll
    for (int kbk = 0; kbk < 8; ++kbk) {
      bf8 ap = *(const bf8*)&Pa[((kbk * 4 + w) * 64 + lane) * 8];
#pragma unroll
      for (int nb = 0; nb < 4; ++nb) {
        bf8 bv = *(const bf8*)&vp[(size_t)(nb * 16 + c) * 4096 + kb0 + kbk * 32 + qd * 8];
        accO[nb] = __builtin_amdgcn_mfma_f32_16x16x32_bf16(ap, bv, accO[nb], 0, 0, 0);
      }
    }
    __syncthreads();
  }
  const size_t ob = ((size_t)kc * 32 + bh) * 256 + r0;
#pragma unroll
  for (int nb = 0; nb < 4; ++nb)
#pragma unroll
    for (int r = 0; r < 4; ++r)
      opart[(ob + w * 16 + qd * 4 + r) * 64 + nb * 16 + c] = accO[nb][r];
  if (tid < 64) {
    mpart[ob + tid] = mRow[tid];
    lpart[ob + tid] = lRow[tid];
  }
}

// ---------------- merge the 8 key-chunk partials -> av ----------------------
__global__ __launch_bounds__(256) void attn3_merge(const float* __restrict__ opart,
                                                   const float* __restrict__ mpart,
                                                   const float* __restrict__ lpart,
                                                   float* __restrict__ av) {
  const int g = blockIdx.x * 256 + threadIdx.x;   // 524288 = 32*256*64
  const int d = g & 63;
  const int idx = g >> 6;                          // bh*256+row
  float mx = -3.0e38f;
#pragma unroll
  for (int p = 0; p < 8; ++p) mx = fmaxf(mx, mpart[p * 8192 + idx]);
  float l = 0.f, o = 0.f;
#pragma unroll
  for (int p = 0; p < 8; ++p) {
    const float wp = __expf(mpart[p * 8192 + idx] - mx);
    l += lpart[p * 8192 + idx] * wp;
    o += opart[(size_t)p * 524288 + (size_t)idx * 64 + d] * wp;
  }
  av[g] = o / l;
}

// ------- w2^T = (z_final @ av)^T : z from hi/lo pair, out bf16 --------------
__global__ __launch_bounds__(256) void zav_gemm_t(const short* __restrict__ zh,
                                                  const short* __restrict__ zl,
                                                  const float* __restrict__ av,
                                                  short* __restrict__ w2tb16) {
  const int bh = blockIdx.x;
  const int rq = blockIdx.y;
  __shared__ float Av[256][64];
  const int tid = threadIdx.x;
#pragma unroll
  for (int u = 0; u < 16; ++u) {
    int t4 = tid + u * 256;
    int row = t4 >> 4, c4 = (t4 & 15) << 2;
    *(float4*)&Av[row][c4] = *(const float4*)&av[(size_t)bh * LM_STRIDE + row * 64 + c4];
  }
  __syncthreads();
  const int d = tid & 63, rg4 = tid >> 6;
  for (int s = 0; s < 16; ++s) {
    const int i = rq * 64 + s * 4 + rg4;
    const short* zrh = zh + (size_t)bh * MM_STRIDE + i * 256;
    const short* zrl = zl + (size_t)bh * MM_STRIDE + i * 256;
    float acc = 0.f;
#pragma unroll 8
    for (int j = 0; j < 256; ++j)
      acc += (bf2f_((unsigned short)zrh[j]) + bf2f_((unsigned short)zrl[j])) * Av[j][d];
    w2tb16[(size_t)bh * LM_STRIDE + d * 256 + i] = (short)f2bf_(acc);
  }
}

// -- attn1+conv: oh = softmax(q@kl^T)@w2 + conv(v) [conv via banded MFMA] ----
__global__ __launch_bounds__(256) void attn1_conv_mfma(const short* __restrict__ qb16,
                                                       const short* __restrict__ klb16,
                                                       const short* __restrict__ w2tb16,
                                                       const short* __restrict__ vT16,
                                                       const float* __restrict__ cw,
                                                       short* __restrict__ ohb16) {
  __shared__ short Pa[16384];               // 64x256 bf16 in A-frag order
  __shared__ float redM[4][64], redS[4][64];
  __shared__ float rowM[64], rowI[64];
  __shared__ float cwS[33];
  const int tid = threadIdx.x;
  const int lane = tid & 63, w = tid >> 6;
  const int qd = lane >> 4, c = lane & 15;
  const int r0 = blockIdx.x * 64;
  const int bh = blockIdx.y;
  const short* qp = qb16 + (size_t)bh * QKV_STRIDE;
  const short* klp = klb16 + (size_t)bh * LM_STRIDE;
  const short* w2p = w2tb16 + (size_t)bh * LM_STRIDE;
  const short* vp = vT16 + (size_t)bh * QKV_STRIDE;

  if (tid < 33) cwS[tid] = cw[(bh & 7) * 33 + tid];

  f32x4 acc[4][4];
#pragma unroll
  for (int i = 0; i < 4; ++i)
#pragma unroll
    for (int j = 0; j < 4; ++j) acc[i][j] = (f32x4){0.f, 0.f, 0.f, 0.f};
#pragma unroll
  for (int st = 0; st < 2; ++st) {
    const int k0 = st * 32 + qd * 8;
    bf8 af[4], bf[4];
#pragma unroll
    for (int i = 0; i < 4; ++i) {
      af[i] = *(const bf8*)&qp[(size_t)(r0 + i * 16 + c) * 64 + k0];
      bf[i] = *(const bf8*)&klp[(size_t)(w * 64 + i * 16 + c) * 64 + k0];
    }
#pragma unroll
    for (int i = 0; i < 4; ++i)
#pragma unroll
      for (int j = 0; j < 4; ++j)
        acc[i][j] = __builtin_amdgcn_mfma_f32_16x16x32_bf16(af[i], bf[j], acc[i][j], 0, 0, 0);
  }
#pragma unroll
  for (int i = 0; i < 4; ++i)
#pragma unroll
    for (int r = 0; r < 4; ++r) {
      float m0 = fmaxf(fmaxf(acc[i][0][r], acc[i][1][r]),
                       fmaxf(acc[i][2][r], acc[i][3][r]));
      m0 = fmaxf(m0, __shfl_xor(m0, 1));
      m0 = fmaxf(m0, __shfl_xor(m0, 2));
      m0 = fmaxf(m0, __shfl_xor(m0, 4));
      m0 = fmaxf(m0, __shfl_xor(m0, 8));
      if (c == 0) redM[w][i * 16 + qd * 4 + r] = m0;
    }
  __syncthreads();
  if (tid < 64)
    rowM[tid] = fmaxf(fmaxf(redM[0][tid], redM[1][tid]),
                      fmaxf(redM[2][tid], redM[3][tid]));
  __syncthreads();
#pragma unroll
  for (int i = 0; i < 4; ++i)
#pragma unroll
    for (int r = 0; r < 4; ++r) {
      const float mrow = rowM[i * 16 + qd * 4 + r];
      float s = 0.f;
#pragma unroll
      for (int j = 0; j < 4; ++j) {
        const float e = __expf(acc[i][j][r] - mrow);
        acc[i][j][r] = e;
        s += e;
      }
      s += __shfl_xor(s, 1);
      s += __shfl_xor(s, 2);
      s += __shfl_xor(s, 4);
      s += __shfl_xor(s, 8);
      if (c == 0) redS[w][i * 16 + qd * 4 + r] = s;
    }
  __syncthreads();
  if (tid < 64)
    rowI[tid] = 1.0f / (redS[0][tid] + redS[1][tid] + redS[2][tid] + redS[3][tid]);
  __syncthreads();
#pragma unroll
  for (int i = 0; i < 4; ++i)
#pragma unroll
    for (int r = 0; r < 4; ++r) {
      const int row = i * 16 + qd * 4 + r;
      const float inv = rowI[row];
#pragma unroll
      for (int j = 0; j < 4; ++j) {
        const int col = w * 64 + j * 16 + c;
        const short val = (short)f2bf_(acc[i][j][r] * inv);
        const int kb = col >> 5;
        const int lane2 = (row & 15) + 16 * ((col >> 3) & 3);
        Pa[((kb * 4 + i) * 64 + lane2) * 8 + (col & 7)] = val;
      }
    }
  __syncthreads();
  f32x4 accO[4];
#pragma unroll
  for (int nb = 0; nb < 4; ++nb) accO[nb] = (f32x4){0.f, 0.f, 0.f, 0.f};
  for (int kb = 0; kb < 8; ++kb) {
    bf8 ap = *(const bf8*)&Pa[((kb * 4 + w) * 64 + lane) * 8];
#pragma unroll
    for (int nb = 0; nb < 4; ++nb) {
      bf8 bfr = *(const bf8*)&w2p[(size_t)(nb * 16 + c) * 256 + kb * 32 + qd * 8];
      accO[nb] = __builtin_amdgcn_mfma_f32_16x16x32_bf16(ap, bfr, accO[nb], 0, 0, 0);
    }
  }
  // conv residual via banded MFMA: out += Band[64x96] @ Vwin[96x64]
  {
    bf8 ba[3];
    const int rl = w * 16 + (lane & 15);
#pragma unroll
    for (int kb = 0; kb < 3; ++kb) {
#pragma unroll
      for (int e = 0; e < 8; ++e) {
        const int kk = kb * 32 + qd * 8 + e;
        const int t = kk - rl;
        const int s = r0 - 16 + kk;
        const float bv = (t >= 0 && t < 33 && s >= 0 && s < 4096) ? cwS[t] : 0.f;
        ba[kb][e] = (short)f2bf_(bv);
      }
    }
#pragma unroll
    for (int kb = 0; kb < 3; ++kb) {
      int s0 = r0 - 16 + kb * 32 + qd * 8;
      s0 = s0 < 0 ? 0 : (s0 > 4088 ? 4088 : s0);
#pragma unroll
      for (int nb = 0; nb < 4; ++nb) {
        bf8 bv = *(const bf8*)&vp[(size_t)(nb * 16 + c) * 4096 + s0];
        accO[nb] = __builtin_amdgcn_mfma_f32_16x16x32_bf16(ba[kb], bv, accO[nb], 0, 0, 0);
      }
    }
  }
  short* ohp = (short*)ohb16 + (size_t)bh * QKV_STRIDE;
#pragma unroll
  for (int nb = 0; nb < 4; ++nb)
#pragma unroll
    for (int r = 0; r < 4; ++r) {
      const int row = r0 + w * 16 + qd * 4 + r;
      ohp[(size_t)row * 64 + nb * 16 + c] = (short)f2bf_(accO[nb][r]);
    }
}

// ------- out = concat_heads(oh_bf16) @ w_out + b_out (MFMA) -----------------
__global__ __launch_bounds__(256) void gemm_out_mfma(const short* __restrict__ ohb16,
                                                     const short* __restrict__ wT,
                                                     const float* __restrict__ bias,
                                                     float* __restrict__ out) {
  __shared__ short As[4096];
  __shared__ short Bs[4096];
  const int tid = threadIdx.x;
  const int lane = tid & 63, w = tid >> 6;
  const int wr = w >> 1, wc = w & 1;
  const int gm0 = blockIdx.x * 128, gn0 = blockIdx.y * 128;
  const int mA0 = (tid >> 6) * 16 + (tid & 15), kA0 = ((tid >> 4) & 3) * 8;
  const int s1 = tid + 256;
  const int mA1 = (s1 >> 6) * 16 + (s1 & 15), kA1 = ((s1 >> 4) & 3) * 8;
  const int b0r = (gm0 + mA0) >> 12, seq0 = (gm0 + mA0) & 4095;
  const int b1r = (gm0 + mA1) >> 12, seq1 = (gm0 + mA1) & 4095;
  f32x4 acc[4][4];
#pragma unroll
  for (int i = 0; i < 4; ++i)
#pragma unroll
    for (int j = 0; j < 4; ++j) acc[i][j] = (f32x4){0.f, 0.f, 0.f, 0.f};
  for (int kt = 0; kt < 16; ++kt) {
    const int k0 = kt * 32;
    const int ka = k0 + kA0, kb = k0 + kA1;
    bf8 aa0 = *(const bf8*)&ohb16[(size_t)(b0r * 8 + (ka >> 6)) * QKV_STRIDE + seq0 * 64 + (ka & 63)];
    bf8 aa1 = *(const bf8*)&ohb16[(size_t)(b1r * 8 + (kb >> 6)) * QKV_STRIDE + seq1 * 64 + (kb & 63)];
    bf8 bb0 = *(const bf8*)&wT[(size_t)(gn0 + mA0) * 512 + ka];
    bf8 bb1 = *(const bf8*)&wT[(size_t)(gn0 + mA1) * 512 + kb];
    __syncthreads();
    *(bf8*)&As[tid * 8] = aa0;
    *(bf8*)&As[s1 * 8] = aa1;
    *(bf8*)&Bs[tid * 8] = bb0;
    *(bf8*)&Bs[s1 * 8] = bb1;
    __syncthreads();
    bf8 af[4], bfr[4];
#pragma unroll
    for (int i = 0; i < 4; ++i) {
      af[i] = *(const bf8*)&As[((wr * 4 + i) * 64 + lane) * 8];
      bfr[i] = *(const bf8*)&Bs[((wc * 4 + i) * 64 + lane) * 8];
    }
#pragma unroll
    for (int i = 0; i < 4; ++i)
#pragma unroll
      for (int j = 0; j < 4; ++j)
        acc[i][j] = __builtin_amdgcn_mfma_f32_16x16x32_bf16(af[i], bfr[j], acc[i][j], 0, 0, 0);
  }
  const int qd = lane >> 4, c = lane & 15;
#pragma unroll
  for (int i = 0; i < 4; ++i)
#pragma unroll
    for (int j = 0; j < 4; ++j) {
      const int col = gn0 + wc * 64 + j * 16 + c;
      const float bval = bias[col];
#pragma unroll
      for (int r = 0; r < 4; ++r) {
        const int row = gm0 + wr * 64 + i * 16 + qd * 4 + r;
        out[(size_t)row * 512 + col] = acc[i][j][r] + bval;
      }
    }
}

// ---------------------------------------------------------------------------
extern "C" void kernel_launch(void* const* d_in, const int* in_sizes, int n_in,
                              void* d_out, int out_size, void* d_ws, size_t ws_size,
                              hipStream_t stream) {
  const float* x    = (const float*)d_in[0];
  const float* wqkv = (const float*)d_in[1];
  const float* wout = (const float*)d_in[2];
  const float* bout = (const float*)d_in[3];
  const float* cw   = (const float*)d_in[4];
  float* out = (float*)d_out;

  float* w = (float*)d_ws;
  short* qb16   = (short*)(w);              // [32,4096,64] bf16
  short* kb16   = (short*)(w + 4194304);
  short* vT16   = (short*)(w + 8388608);    // [32,64,4096] bf16
  short* ohb16  = (short*)(w + 12582912);
  float* ql     = w + 16777216;             // [32,256,64] fp32
  float* kl     = w + 17301504;
  short* klb16  = (short*)(w + 17825792);
  float* x2     = w + 18087936;             // [32,256,256] fp32
  // bf16 hi/lo pair arrays, each 1048576 floats (2M bf16):
  short* x2h  = (short*)(w + 20185088);
  short* x2l  = (short*)(w + 21233664);
  short* z0h  = (short*)(w + 22282240);
  short* z0l  = (short*)(w + 23330816);
  short* z0th = (short*)(w + 24379392);
  short* z0tl = (short*)(w + 25427968);
  short* z1h  = (short*)(w + 26476544);
  short* z1l  = (short*)(w + 27525120);
  short* z1th = (short*)(w + 28573696);
  short* z1tl = (short*)(w + 29622272);
  short* xzh  = (short*)(w + 30670848);
  short* xzl  = (short*)(w + 31719424);
  short* xzth = (short*)(w + 32768000);
  short* xztl = (short*)(w + 33816576);
  short* u1th = (short*)(w + 34865152);
  short* u1tl = (short*)(w + 35913728);
  short* u2th = (short*)(w + 36962304);
  short* u2tl = (short*)(w + 38010880);
  float* av     = w + 39059456;             // [32,256,64] fp32
  short* w2tb16 = (short*)(w + 39583744);
  float* scal   = w + 39845888;             // [2]
  short* wqkvT  = (short*)(w + 39845952);
  short* woutT  = (short*)(w + 40239168);   // ends 40370240 floats (~162 MB)
  // aliases valid only AFTER the pinv loop (xz*/u1t* dead; final z in z0 set):
  float* opart = w + 30670848;              // [8,32,256,64] fp32 = 16 MB (xz set)
  float* mpart = w + 34865152;              // [8,32,256] (u1th)
  float* lpart = w + 34865152 + 65536;      // [8,32,256]

  zero_scal<<<1, 64, 0, stream>>>(scal);
  transpose_bf16<<<dim3(48, 16), 256, 0, stream>>>(wqkv, wqkvT, 512, 1536);
  transpose_bf16<<<dim3(16, 16), 256, 0, stream>>>(wout, woutT, 512, 512);
  gemm_qkv_mfma<<<dim3(128, 12), 256, 0, stream>>>(x, wqkvT, qb16, kb16, vT16);
  lmk_mean<<<2048, 256, 0, stream>>>(qb16, kb16, ql, kl, klb16);
  sim2_softmax<<<512, 256, 0, stream>>>(ql, kl, x2);
  colrow_max<<<32, 256, 0, stream>>>(x2, scal);
  x2split<<<8192, 256, 0, stream>>>(x2, x2h, x2l);
  tscale_split<<<512, 256, 0, stream>>>(x2, scal, z0h, z0l, z0th, z0tl);

  short *zch = z0h, *zcl = z0l, *zcth = z0th, *zctl = z0tl;
  short *znh = z1h, *znl = z1l, *znth = z1th, *zntl = z1tl;
  for (int it = 0; it < 6; ++it) {
    // xz = x2 @ z
    pinv_mfma<<<1024, 256, 0, stream>>>(x2h, x2l, zcth, zctl, x2h, x2l,
                                        xzh, xzl, xzth, xztl, 0.f, 1.f, 1, 1);
    // u1 = 7*xz - xz@xz   (T output only)
    pinv_mfma<<<1024, 256, 0, stream>>>(xzh, xzl, xzth, xztl, xzh, xzl,
                                        u1th, u1tl, u1th, u1tl, 7.f, -1.f, 0, 1);
    // u2 = 15*xz - xz@u1  (T output only)
    pinv_mfma<<<1024, 256, 0, stream>>>(xzh, xzl, u1th, u1tl, xzh, xzl,
                                        u2th, u2tl, u2th, u2tl, 15.f, -1.f, 0, 1);
    // zn = 3.25*z - 0.25*(z@u2)
    pinv_mfma<<<1024, 256, 0, stream>>>(zch, zcl, u2th, u2tl, zch, zcl,
                                        znh, znl, znth, zntl, 3.25f, -0.25f, 1, 1);
    short* t;
    t = zch; zch = znh; znh = t;
    t = zcl; zcl = znl; znl = t;
    t = zcth; zcth = znth; znth = t;
    t = zctl; zctl = zntl; zntl = t;
  }
  // zc == z0 set here; xz*/u1t* dead -> opart/mpart/lpart aliases live.

  attn3_flash<<<dim3(8, 4, 32), 256, 0, stream>>>(ql, kb16, vT16, opart, mpart, lpart);
  attn3_merge<<<2048, 256, 0, stream>>>(opart, mpart, lpart, av);
  zav_gemm_t<<<dim3(32, 4), 256, 0, stream>>>(zch, zcl, av, w2tb16);
  attn1_conv_mfma<<<dim3(64, 32), 256, 0, stream>>>(qb16, klb16, w2tb16, vT16, cw, ohb16);
  gemm_out_mfma<<<dim3(128, 4), 256, 0, stream>>>(ohb16, woutT, bout, out);
}

// Round 7
// 880.599 us; speedup vs baseline: 1.3381x; 1.3381x over previous
//
#include <hip/hip_runtime.h>
#include <math.h>

// ---------------------------------------------------------------------------
// NystromAttention round 7: R5 structure + per-wave barrier-free attn3 flash
// + L2-friendly 1-D grid order for qkv/out GEMMs. (R6's pinv/kc changes
// reverted: pair storage saved no bytes and broke coalescing.)
// b=4 n=4096 dim=512 h=8 d=64 m=256, l=16, iters=6, conv k=33.
// MFMA 16x16x32_bf16 layouts (HW-verified per guide):
//   A: m=lane&15, k=(lane>>4)*8+j    B: n=lane&15, k=(lane>>4)*8+j
//   C/D: col=lane&15, row=(lane>>4)*4+reg
// ---------------------------------------------------------------------------

#define QKV_STRIDE 262144   // 4096*64 per (b,h)
#define LM_STRIDE 16384     // 256*64
#define MM_STRIDE 65536     // 256*256

typedef float f32x4 __attribute__((ext_vector_type(4)));
typedef short bf8 __attribute__((ext_vector_type(8)));   // 8 bf16 in 4 VGPRs
typedef short s4v __attribute__((ext_vector_type(4)));

__device__ __forceinline__ unsigned short f2bf_(float f) {
  unsigned u = __float_as_uint(f);
  u += 0x7FFFu + ((u >> 16) & 1u);   // RNE
  return (unsigned short)(u >> 16);
}
__device__ __forceinline__ float bf2f_(unsigned short h) {
  return __uint_as_float(((unsigned)h) << 16);
}
__device__ __forceinline__ bf8 pack8(const float4 a, const float4 b) {
  bf8 r;
  r[0] = (short)f2bf_(a.x); r[1] = (short)f2bf_(a.y);
  r[2] = (short)f2bf_(a.z); r[3] = (short)f2bf_(a.w);
  r[4] = (short)f2bf_(b.x); r[5] = (short)f2bf_(b.y);
  r[6] = (short)f2bf_(b.z); r[7] = (short)f2bf_(b.w);
  return r;
}

__global__ __launch_bounds__(256) void zero_scal(float* scal) {
  if (threadIdx.x < 2) scal[threadIdx.x] = 0.0f;
}

// ------------- transpose + fp32->bf16: dst[C][R] = bf16(src[R][C]) ----------
__global__ __launch_bounds__(256) void transpose_bf16(const float* __restrict__ src,
                                                      short* __restrict__ dst,
                                                      int R, int C) {
  __shared__ float T[32][33];
  const int t = threadIdx.x;
  const int c0 = blockIdx.x * 32, r0 = blockIdx.y * 32;
  const int tr = t >> 3, tc = (t & 7) << 2;
  float4 vsrc = *(const float4*)&src[(size_t)(r0 + tr) * C + c0 + tc];
  T[tr][tc + 0] = vsrc.x; T[tr][tc + 1] = vsrc.y;
  T[tr][tc + 2] = vsrc.z; T[tr][tc + 3] = vsrc.w;
  __syncthreads();
  s4v o;
  o[0] = (short)f2bf_(T[tc + 0][tr]);
  o[1] = (short)f2bf_(T[tc + 1][tr]);
  o[2] = (short)f2bf_(T[tc + 2][tr]);
  o[3] = (short)f2bf_(T[tc + 3][tr]);
  *(s4v*)&dst[(size_t)(c0 + tr) * R + r0 + tc] = o;
}

// ---- qkv = x @ w_qkv via MFMA -> qb16/kb16 row-major bf16, vT16 bf16 -------
// 1-D grid, bn fastest: 12 consecutive blocks share one x-tile (L2 reuse).
__global__ __launch_bounds__(256) void gemm_qkv_mfma(const float* __restrict__ x,
                                                     const short* __restrict__ wT,
                                                     short* __restrict__ qb16,
                                                     short* __restrict__ kb16,
                                                     short* __restrict__ vT16) {
  __shared__ short SMEM[17408];   // As[0..4095], Bs[4096..8191]; v: stage 128x136
  short* As = SMEM;
  short* Bs = SMEM + 4096;
  const int tid = threadIdx.x;
  const int lane = tid & 63, w = tid >> 6;
  const int wr = w >> 1, wc = w & 1;
  const int bn = blockIdx.x % 12, bm = blockIdx.x / 12;
  const int gm0 = bm * 128, gn0 = bn * 128;
  const int mA0 = (tid >> 6) * 16 + (tid & 15), kA0 = ((tid >> 4) & 3) * 8;
  const int s1 = tid + 256;
  const int mA1 = (s1 >> 6) * 16 + (s1 & 15), kA1 = ((s1 >> 4) & 3) * 8;
  f32x4 acc[4][4];
#pragma unroll
  for (int i = 0; i < 4; ++i)
#pragma unroll
    for (int j = 0; j < 4; ++j) acc[i][j] = (f32x4){0.f, 0.f, 0.f, 0.f};
  for (int kt = 0; kt < 16; ++kt) {
    const int k0 = kt * 32;
    float4 a0 = *(const float4*)&x[(size_t)(gm0 + mA0) * 512 + k0 + kA0];
    float4 a1 = *(const float4*)&x[(size_t)(gm0 + mA0) * 512 + k0 + kA0 + 4];
    float4 a2 = *(const float4*)&x[(size_t)(gm0 + mA1) * 512 + k0 + kA1];
    float4 a3 = *(const float4*)&x[(size_t)(gm0 + mA1) * 512 + k0 + kA1 + 4];
    bf8 b0 = *(const bf8*)&wT[(size_t)(gn0 + mA0) * 512 + k0 + kA0];
    bf8 b1 = *(const bf8*)&wT[(size_t)(gn0 + mA1) * 512 + k0 + kA1];
    __syncthreads();
    *(bf8*)&As[tid * 8] = pack8(a0, a1);
    *(bf8*)&As[s1 * 8] = pack8(a2, a3);
    *(bf8*)&Bs[tid * 8] = b0;
    *(bf8*)&Bs[s1 * 8] = b1;
    __syncthreads();
    bf8 af[4], bf[4];
#pragma unroll
    for (int i = 0; i < 4; ++i) {
      af[i] = *(const bf8*)&As[((wr * 4 + i) * 64 + lane) * 8];
      bf[i] = *(const bf8*)&Bs[((wc * 4 + i) * 64 + lane) * 8];
    }
#pragma unroll
    for (int i = 0; i < 4; ++i)
#pragma unroll
      for (int j = 0; j < 4; ++j)
        acc[i][j] = __builtin_amdgcn_mfma_f32_16x16x32_bf16(af[i], bf[j], acc[i][j], 0, 0, 0);
  }
  const int which = bn >> 2;  // 0:q 1:k 2:v
  const int qd = lane >> 4, c = lane & 15;
  if (which < 2) {
    short* dst = which == 0 ? qb16 : kb16;
    const float scale = which == 0 ? 0.125f : 1.0f;
#pragma unroll
    for (int i = 0; i < 4; ++i)
#pragma unroll
      for (int j = 0; j < 4; ++j) {
        const int col = gn0 + wc * 64 + j * 16 + c;
        const int head = (col >> 6) & 7, dd = col & 63;
#pragma unroll
        for (int r = 0; r < 4; ++r) {
          const int row = gm0 + wr * 64 + i * 16 + qd * 4 + r;
          const int b = row >> 12, seq = row & 4095;
          dst[(size_t)(b * 8 + head) * QKV_STRIDE + seq * 64 + dd] =
              (short)f2bf_(acc[i][j][r] * scale);
        }
      }
  } else {
    __syncthreads();
#pragma unroll
    for (int i = 0; i < 4; ++i)
#pragma unroll
      for (int j = 0; j < 4; ++j) {
        const int colL = wc * 64 + j * 16 + c;
#pragma unroll
        for (int r = 0; r < 4; ++r) {
          const int rowL = wr * 64 + i * 16 + qd * 4 + r;
          SMEM[colL * 136 + rowL] = (short)f2bf_(acc[i][j][r]);
        }
      }
    __syncthreads();
    const int b = gm0 >> 12, seq0 = gm0 & 4095;
    const int dcol = tid >> 1, half = tid & 1;
    const int col = gn0 + dcol;
    const int head = (col >> 6) & 7, d = col & 63;
    const short* src = &SMEM[dcol * 136 + half * 64];
    short* dstp = &vT16[(size_t)(b * 8 + head) * QKV_STRIDE + (size_t)d * 4096 +
                        seq0 + half * 64];
#pragma unroll
    for (int u = 0; u < 16; ++u) *(s4v*)&dstp[u * 4] = *(const s4v*)&src[u * 4];
  }
}

// ---------------- landmark means (bf16 in, fp32 + bf16-kl out) --------------
__global__ __launch_bounds__(256) void lmk_mean(const short* __restrict__ qb16,
                                                const short* __restrict__ kb16,
                                                float* __restrict__ ql,
                                                float* __restrict__ kl,
                                                short* __restrict__ klb16) {
  const int g = blockIdx.x * 256 + threadIdx.x;
  const int dd = g & 63, mi = (g >> 6) & 255, bh = g >> 14;
  const size_t base = (size_t)bh * QKV_STRIDE + mi * 1024 + dd;
  float sq = 0.f, sk = 0.f;
#pragma unroll
  for (int jj = 0; jj < 16; ++jj) {
    sq += bf2f_((unsigned short)qb16[base + jj * 64]);
    sk += bf2f_((unsigned short)kb16[base + jj * 64]);
  }
  const float qv = sq * 0.0625f, kv = sk * 0.0625f;
  ql[g] = qv;
  kl[g] = kv;
  klb16[g] = (short)f2bf_(kv);
}

// ---------------- sim2 = ql @ kl^T, softmax -> x2 ---------------------------
__global__ __launch_bounds__(256) void sim2_softmax(const float* __restrict__ ql,
                                                    const float* __restrict__ kl,
                                                    float* __restrict__ x2) {
  const int blk = blockIdx.x;
  const int bh = blk >> 4, rg = blk & 15;
  __shared__ float Qs[16][64];
  __shared__ float Ks[64][68];
  __shared__ float S[16][257];
  __shared__ float red[16][17];
  __shared__ float rowinv[16];
  const int tid = threadIdx.x;
  const int r = tid >> 4, jc = tid & 15;
#pragma unroll
  for (int u = 0; u < 4; ++u) {
    int t2 = tid + u * 256;
    Qs[t2 >> 6][t2 & 63] =
        ql[(size_t)bh * LM_STRIDE + (rg * 16 + (t2 >> 6)) * 64 + (t2 & 63)];
  }
  for (int c = 0; c < 4; ++c) {
    __syncthreads();
#pragma unroll
    for (int u = 0; u < 4; ++u) {
      int t4 = tid + u * 256;
      int row = t4 >> 4, c4 = (t4 & 15) << 2;
      *(float4*)&Ks[row][c4] =
          *(const float4*)&kl[(size_t)bh * LM_STRIDE + (c * 64 + row) * 64 + c4];
    }
    __syncthreads();
#pragma unroll
    for (int s = 0; s < 4; ++s) {
      const int jj = jc + (s << 4);
      float acc = 0.f;
#pragma unroll
      for (int k4 = 0; k4 < 16; ++k4) {
        const float4 a = *(const float4*)&Qs[r][k4 << 2];
        const float4 bb = *(const float4*)&Ks[jj][k4 << 2];
        acc += a.x * bb.x + a.y * bb.y + a.z * bb.z + a.w * bb.w;
      }
      S[r][(c << 6) + jj] = acc;
    }
  }
  __syncthreads();
  float pm = -3.0e38f;
#pragma unroll
  for (int u = 0; u < 16; ++u) pm = fmaxf(pm, S[r][jc + (u << 4)]);
  red[r][jc] = pm;
  __syncthreads();
  float m = red[r][0];
#pragma unroll
  for (int u = 1; u < 16; ++u) m = fmaxf(m, red[r][u]);
  __syncthreads();
  float ps = 0.f;
#pragma unroll
  for (int u = 0; u < 16; ++u) {
    const int j = jc + (u << 4);
    const float e = __expf(S[r][j] - m);
    S[r][j] = e;
    ps += e;
  }
  red[r][jc] = ps;
  __syncthreads();
  if (jc == 0) {
    float sum = 0.f;
#pragma unroll
    for (int u = 0; u < 16; ++u) sum += red[r][u];
    rowinv[r] = 1.0f / sum;
  }
  __syncthreads();
  for (int idx = tid; idx < 4096; idx += 256) {
    const int rr = idx >> 8, j = idx & 255;
    x2[(size_t)bh * MM_STRIDE + (rg * 16 + rr) * 256 + j] = S[rr][j] * rowinv[rr];
  }
}

// ---------------- global max of col/row abs-sums ----------------------------
__global__ __launch_bounds__(256) void colrow_max(const float* __restrict__ x2,
                                                  float* __restrict__ scal) {
  const int bh = blockIdx.x;
  const int tid = threadIdx.x;
  const float* xb = x2 + (size_t)bh * MM_STRIDE;
  float cs = 0.f, rs = 0.f;
  for (int j = 0; j < 256; ++j) cs += fabsf(xb[tid * 256 + j]);
  for (int i = 0; i < 256; ++i) rs += fabsf(xb[i * 256 + tid]);
  __shared__ float rc[256], rr[256];
  rc[tid] = cs; rr[tid] = rs;
  __syncthreads();
  for (int st = 128; st > 0; st >>= 1) {
    if (tid < st) {
      rc[tid] = fmaxf(rc[tid], rc[tid + st]);
      rr[tid] = fmaxf(rr[tid], rr[tid + st]);
    }
    __syncthreads();
  }
  if (tid == 0) {
    atomicMax((int*)&scal[0], __float_as_int(rc[0]));
    atomicMax((int*)&scal[1], __float_as_int(rr[0]));
  }
}

// --------- z0 = x2^T/(cmax*rmax), z0t = x2/(cmax*rmax) ----------------------
__global__ __launch_bounds__(256) void tscale2(const float* __restrict__ x2,
                                               const float* __restrict__ scal,
                                               float* __restrict__ z0,
                                               float* __restrict__ z0t) {
  const int g = blockIdx.x * 256 + threadIdx.x;
  const int j = g & 255, i = (g >> 8) & 255, bh = g >> 16;
  const float inv = 1.0f / (scal[0] * scal[1]);
  const float val = x2[g] * inv;      // x2[bh][i][j]
  z0t[g] = val;
  z0[(size_t)bh * MM_STRIDE + j * 256 + i] = val;
}

// --------- split-bf16 batched 256^3: C = alpha*E + beta*(A@B) ---------------
// (R5 version: LDS-staged, XCD-swizzled 1-D grid, LDS-transposed CT writes.)
__global__ __launch_bounds__(256) void pinv_mfma(const float* __restrict__ A,
                                                 const float* __restrict__ BT,
                                                 const float* __restrict__ E,
                                                 float* __restrict__ C,
                                                 float* __restrict__ CT,
                                                 float alpha, float beta,
                                                 int wantC, int wantT) {
  __shared__ short Ahi[2048], Alo[2048], Bhi[2048], Blo[2048];
  __shared__ float Tbuf[64 * 68];
  const int tid = threadIdx.x;
  const int lane = tid & 63, w = tid >> 6;
  const int bid = blockIdx.x;
  const int xcd = bid & 7, y = bid >> 3;
  const int t16 = y & 15, bgrp = y >> 4;
  const int batch = bgrp * 8 + xcd;
  const int tm = t16 >> 2, tn = t16 & 3;
  const float* Ab = A + (size_t)batch * MM_STRIDE;
  const float* BTb = BT + (size_t)batch * MM_STRIDE;
  const float* Eb = E + (size_t)batch * MM_STRIDE;
  const int ml = (tid >> 6) * 16 + (tid & 15), koff = ((tid >> 4) & 3) * 8;
  f32x4 acc[4];
#pragma unroll
  for (int j = 0; j < 4; ++j) acc[j] = (f32x4){0.f, 0.f, 0.f, 0.f};
  for (int kt = 0; kt < 8; ++kt) {
    const int k0 = kt * 32;
    float4 a0 = *(const float4*)&Ab[(size_t)(tm * 64 + ml) * 256 + k0 + koff];
    float4 a1 = *(const float4*)&Ab[(size_t)(tm * 64 + ml) * 256 + k0 + koff + 4];
    float4 b0 = *(const float4*)&BTb[(size_t)(tn * 64 + ml) * 256 + k0 + koff];
    float4 b1 = *(const float4*)&BTb[(size_t)(tn * 64 + ml) * 256 + k0 + koff + 4];
    __syncthreads();
    {
      bf8 hi, lo;
      const float fa[8] = {a0.x, a0.y, a0.z, a0.w, a1.x, a1.y, a1.z, a1.w};
#pragma unroll
      for (int e = 0; e < 8; ++e) {
        unsigned short h = f2bf_(fa[e]);
        hi[e] = (short)h;
        lo[e] = (short)f2bf_(fa[e] - bf2f_(h));
      }
      *(bf8*)&Ahi[tid * 8] = hi;
      *(bf8*)&Alo[tid * 8] = lo;
      const float fb[8] = {b0.x, b0.y, b0.z, b0.w, b1.x, b1.y, b1.z, b1.w};
#pragma unroll
      for (int e = 0; e < 8; ++e) {
        unsigned short h = f2bf_(fb[e]);
        hi[e] = (short)h;
        lo[e] = (short)f2bf_(fb[e] - bf2f_(h));
      }
      *(bf8*)&Bhi[tid * 8] = hi;
      *(bf8*)&Blo[tid * 8] = lo;
    }
    __syncthreads();
    bf8 ah = *(const bf8*)&Ahi[(w * 64 + lane) * 8];
    bf8 al = *(const bf8*)&Alo[(w * 64 + lane) * 8];
#pragma unroll
    for (int j = 0; j < 4; ++j) {
      bf8 bh = *(const bf8*)&Bhi[(j * 64 + lane) * 8];
      bf8 bl = *(const bf8*)&Blo[(j * 64 + lane) * 8];
      acc[j] = __builtin_amdgcn_mfma_f32_16x16x32_bf16(ah, bh, acc[j], 0, 0, 0);
      acc[j] = __builtin_amdgcn_mfma_f32_16x16x32_bf16(ah, bl, acc[j], 0, 0, 0);
      acc[j] = __builtin_amdgcn_mfma_f32_16x16x32_bf16(al, bh, acc[j], 0, 0, 0);
    }
  }
  float* Cb = C + (size_t)batch * MM_STRIDE;
  float* CTb = CT + (size_t)batch * MM_STRIDE;
  const int qd = lane >> 4, c = lane & 15;
  float vals[4][4];
#pragma unroll
  for (int j = 0; j < 4; ++j) {
    const int col = tn * 64 + j * 16 + c;
#pragma unroll
    for (int r = 0; r < 4; ++r) {
      const int row = tm * 64 + w * 16 + qd * 4 + r;
      vals[j][r] = alpha * Eb[(size_t)row * 256 + col] + beta * acc[j][r];
      if (wantC) Cb[(size_t)row * 256 + col] = vals[j][r];
    }
  }
  if (wantT) {
    __syncthreads();
#pragma unroll
    for (int j = 0; j < 4; ++j)
#pragma unroll
      for (int r = 0; r < 4; ++r)
        Tbuf[(j * 16 + c) * 68 + w * 16 + qd * 4 + r] = vals[j][r];
    __syncthreads();
    const int ctr = tid >> 2, seg = (tid & 3) * 16;
#pragma unroll
    for (int u = 0; u < 4; ++u) {
      float4 o = *(const float4*)&Tbuf[ctr * 68 + seg + u * 4];
      *(float4*)&CTb[(size_t)(tn * 64 + ctr) * 256 + tm * 64 + seg + u * 4] = o;
    }
  }
}

// ---- attn3 flash, per-wave (barrier-free): each wave owns 16 ql rows -------
__global__ __launch_bounds__(256) void attn3_flash(const float* __restrict__ ql,
                                                   const short* __restrict__ kb16,
                                                   const short* __restrict__ vT16,
                                                   float* __restrict__ opart,
                                                   float* __restrict__ mpart,
                                                   float* __restrict__ lpart) {
  const int kc = blockIdx.x;   // key chunk 0..3 (1024 keys each)
  const int rt = blockIdx.y;   // row tile 0..3 (64 rows each)
  const int bh = blockIdx.z;   // 0..31
  __shared__ short Pa[4][4096];  // per-wave 16 rows x 256 keys, A-frag order
  const int tid = threadIdx.x, lane = tid & 63, w = tid >> 6;
  const int qd = lane >> 4, c = lane & 15;
  const int rw = rt * 64 + w * 16;               // wave's first global row
  const float* qlp = ql + (size_t)bh * LM_STRIDE;
  const short* kp = kb16 + (size_t)bh * QKV_STRIDE;
  const short* vp = vT16 + (size_t)bh * QKV_STRIDE;
  short* Pw = &Pa[w][0];
  // A-frags for the wave's 16 rows
  bf8 af[2];
#pragma unroll
  for (int st = 0; st < 2; ++st) {
    float4 x0 = *(const float4*)&qlp[(size_t)(rw + c) * 64 + st * 32 + qd * 8];
    float4 x1 = *(const float4*)&qlp[(size_t)(rw + c) * 64 + st * 32 + qd * 8 + 4];
    af[st] = pack8(x0, x1);
  }
  float m[4], l[4];
#pragma unroll
  for (int r = 0; r < 4; ++r) { m[r] = -3.0e38f; l[r] = 0.f; }
  f32x4 accO[4];
#pragma unroll
  for (int nb = 0; nb < 4; ++nb) accO[nb] = (f32x4){0.f, 0.f, 0.f, 0.f};
  for (int it = 0; it < 4; ++it) {
    const int kb0 = kc * 1024 + it * 256;
    f32x4 acc[16];
#pragma unroll
    for (int j = 0; j < 16; ++j) acc[j] = (f32x4){0.f, 0.f, 0.f, 0.f};
#pragma unroll
    for (int st = 0; st < 2; ++st)
#pragma unroll
      for (int j = 0; j < 16; ++j) {
        bf8 bfk = *(const bf8*)&kp[(size_t)(kb0 + j * 16 + c) * 64 + st * 32 + qd * 8];
        acc[j] = __builtin_amdgcn_mfma_f32_16x16x32_bf16(af[st], bfk, acc[j], 0, 0, 0);
      }
    // in-register row stats (rows qd*4+r; reduce over 16 c-lanes)
#pragma unroll
    for (int r = 0; r < 4; ++r) {
      float mx = acc[0][r];
#pragma unroll
      for (int j = 1; j < 16; ++j) mx = fmaxf(mx, acc[j][r]);
      mx = fmaxf(mx, __shfl_xor(mx, 1));
      mx = fmaxf(mx, __shfl_xor(mx, 2));
      mx = fmaxf(mx, __shfl_xor(mx, 4));
      mx = fmaxf(mx, __shfl_xor(mx, 8));
      const float mN = fmaxf(m[r], mx);
      const float a = __expf(m[r] - mN);
      m[r] = mN;
      l[r] *= a;
#pragma unroll
      for (int nb = 0; nb < 4; ++nb) accO[nb][r] *= a;
      float s = 0.f;
#pragma unroll
      for (int j = 0; j < 16; ++j) {
        const float e = __expf(acc[j][r] - mN);
        acc[j][r] = e;
        s += e;
      }
      s += __shfl_xor(s, 1);
      s += __shfl_xor(s, 2);
      s += __shfl_xor(s, 4);
      s += __shfl_xor(s, 8);
      l[r] += s;
    }
    // P -> wave-private LDS in A-frag order (k = key)
#pragma unroll
    for (int j = 0; j < 16; ++j) {
      const int kcol = j * 16 + c;
      const int kb8 = kcol >> 5;
      const int la_base = 16 * ((kcol >> 3) & 3);
      const int j8 = kcol & 7;
#pragma unroll
      for (int r = 0; r < 4; ++r) {
        const int rl = qd * 4 + r;
        Pw[(kb8 * 64 + la_base + rl) * 8 + j8] = (short)f2bf_(acc[j][r]);
      }
    }
    // O += P @ V (no barrier needed: same-wave LDS dependency)
#pragma unroll
    for (int kbk = 0; kbk < 8; ++kbk) {
      bf8 ap = *(const bf8*)&Pw[(kbk * 64 + lane) * 8];
#pragma unroll
      for (int nb = 0; nb < 4; ++nb) {
        bf8 bv = *(const bf8*)&vp[(size_t)(nb * 16 + c) * 4096 + kb0 + kbk * 32 + qd * 8];
        accO[nb] = __builtin_amdgcn_mfma_f32_16x16x32_bf16(ap, bv, accO[nb], 0, 0, 0);
      }
    }
  }
  const size_t ob = ((size_t)kc * 32 + bh) * 256 + rt * 64;
#pragma unroll
  for (int nb = 0; nb < 4; ++nb)
#pragma unroll
    for (int r = 0; r < 4; ++r)
      opart[(ob + w * 16 + qd * 4 + r) * 64 + nb * 16 + c] = accO[nb][r];
  if (c == 0) {
#pragma unroll
    for (int r = 0; r < 4; ++r) {
      mpart[ob + w * 16 + qd * 4 + r] = m[r];
      lpart[ob + w * 16 + qd * 4 + r] = l[r];
    }
  }
}

// ---------------- merge the 4 key-chunk partials -> av ----------------------
__global__ __launch_bounds__(256) void attn3_merge(const float* __restrict__ opart,
                                                   const float* __restrict__ mpart,
                                                   const float* __restrict__ lpart,
                                                   float* __restrict__ av) {
  const int g = blockIdx.x * 256 + threadIdx.x;   // 524288 = 32*256*64
  const int d = g & 63;
  const int idx = g >> 6;                          // bh*256+row
  const float m0 = mpart[idx], m1 = mpart[8192 + idx],
              m2 = mpart[16384 + idx], m3 = mpart[24576 + idx];
  const float mx = fmaxf(fmaxf(m0, m1), fmaxf(m2, m3));
  const float w0 = __expf(m0 - mx), w1 = __expf(m1 - mx),
              w2 = __expf(m2 - mx), w3 = __expf(m3 - mx);
  const float l = lpart[idx] * w0 + lpart[8192 + idx] * w1 +
                  lpart[16384 + idx] * w2 + lpart[24576 + idx] * w3;
  const float o = opart[(size_t)idx * 64 + d] * w0 +
                  opart[524288 + (size_t)idx * 64 + d] * w1 +
                  opart[1048576 + (size_t)idx * 64 + d] * w2 +
                  opart[1572864 + (size_t)idx * 64 + d] * w3;
  av[g] = o / l;
}

// ------- w2^T = (z_final @ av)^T : stores bf16 w2tb16[d][i] -----------------
__global__ __launch_bounds__(256) void zav_gemm_t(const float* __restrict__ z,
                                                  const float* __restrict__ av,
                                                  short* __restrict__ w2tb16) {
  const int bh = blockIdx.x;
  const int rq = blockIdx.y;
  __shared__ float Av[256][64];
  const int tid = threadIdx.x;
#pragma unroll
  for (int u = 0; u < 16; ++u) {
    int t4 = tid + u * 256;
    int row = t4 >> 4, c4 = (t4 & 15) << 2;
    *(float4*)&Av[row][c4] = *(const float4*)&av[(size_t)bh * LM_STRIDE + row * 64 + c4];
  }
  __syncthreads();
  const int d = tid & 63, rg4 = tid >> 6;
  for (int s = 0; s < 16; ++s) {
    const int i = rq * 64 + s * 4 + rg4;
    const float* zr = z + (size_t)bh * MM_STRIDE + i * 256;
    float acc = 0.f;
#pragma unroll 8
    for (int j = 0; j < 256; ++j) acc += zr[j] * Av[j][d];
    w2tb16[(size_t)bh * LM_STRIDE + d * 256 + i] = (short)f2bf_(acc);
  }
}

// -- attn1+conv: oh = softmax(q@kl^T)@w2 + conv(v) [conv via banded MFMA] ----
__global__ __launch_bounds__(256) void attn1_conv_mfma(const short* __restrict__ qb16,
                                                       const short* __restrict__ klb16,
                                                       const short* __restrict__ w2tb16,
                                                       const short* __restrict__ vT16,
                                                       const float* __restrict__ cw,
                                                       short* __restrict__ ohb16) {
  __shared__ short Pa[16384];               // 64x256 bf16 in A-frag order
  __shared__ float redM[4][64], redS[4][64];
  __shared__ float rowM[64], rowI[64];
  __shared__ float cwS[33];
  const int tid = threadIdx.x;
  const int lane = tid & 63, w = tid >> 6;
  const int qd = lane >> 4, c = lane & 15;
  const int r0 = blockIdx.x * 64;
  const int bh = blockIdx.y;
  const short* qp = qb16 + (size_t)bh * QKV_STRIDE;
  const short* klp = klb16 + (size_t)bh * LM_STRIDE;
  const short* w2p = w2tb16 + (size_t)bh * LM_STRIDE;
  const short* vp = vT16 + (size_t)bh * QKV_STRIDE;

  if (tid < 33) cwS[tid] = cw[(bh & 7) * 33 + tid];

  f32x4 acc[4][4];
#pragma unroll
  for (int i = 0; i < 4; ++i)
#pragma unroll
    for (int j = 0; j < 4; ++j) acc[i][j] = (f32x4){0.f, 0.f, 0.f, 0.f};
#pragma unroll
  for (int st = 0; st < 2; ++st) {
    const int k0 = st * 32 + qd * 8;
    bf8 af[4], bf[4];
#pragma unroll
    for (int i = 0; i < 4; ++i) {
      af[i] = *(const bf8*)&qp[(size_t)(r0 + i * 16 + c) * 64 + k0];
      bf[i] = *(const bf8*)&klp[(size_t)(w * 64 + i * 16 + c) * 64 + k0];
    }
#pragma unroll
    for (int i = 0; i < 4; ++i)
#pragma unroll
      for (int j = 0; j < 4; ++j)
        acc[i][j] = __builtin_amdgcn_mfma_f32_16x16x32_bf16(af[i], bf[j], acc[i][j], 0, 0, 0);
  }
#pragma unroll
  for (int i = 0; i < 4; ++i)
#pragma unroll
    for (int r = 0; r < 4; ++r) {
      float m0 = fmaxf(fmaxf(acc[i][0][r], acc[i][1][r]),
                       fmaxf(acc[i][2][r], acc[i][3][r]));
      m0 = fmaxf(m0, __shfl_xor(m0, 1));
      m0 = fmaxf(m0, __shfl_xor(m0, 2));
      m0 = fmaxf(m0, __shfl_xor(m0, 4));
      m0 = fmaxf(m0, __shfl_xor(m0, 8));
      if (c == 0) redM[w][i * 16 + qd * 4 + r] = m0;
    }
  __syncthreads();
  if (tid < 64)
    rowM[tid] = fmaxf(fmaxf(redM[0][tid], redM[1][tid]),
                      fmaxf(redM[2][tid], redM[3][tid]));
  __syncthreads();
#pragma unroll
  for (int i = 0; i < 4; ++i)
#pragma unroll
    for (int r = 0; r < 4; ++r) {
      const float mrow = rowM[i * 16 + qd * 4 + r];
      float s = 0.f;
#pragma unroll
      for (int j = 0; j < 4; ++j) {
        const float e = __expf(acc[i][j][r] - mrow);
        acc[i][j][r] = e;
        s += e;
      }
      s += __shfl_xor(s, 1);
      s += __shfl_xor(s, 2);
      s += __shfl_xor(s, 4);
      s += __shfl_xor(s, 8);
      if (c == 0) redS[w][i * 16 + qd * 4 + r] = s;
    }
  __syncthreads();
  if (tid < 64)
    rowI[tid] = 1.0f / (redS[0][tid] + redS[1][tid] + redS[2][tid] + redS[3][tid]);
  __syncthreads();
#pragma unroll
  for (int i = 0; i < 4; ++i)
#pragma unroll
    for (int r = 0; r < 4; ++r) {
      const int row = i * 16 + qd * 4 + r;
      const float inv = rowI[row];
#pragma unroll
      for (int j = 0; j < 4; ++j) {
        const int col = w * 64 + j * 16 + c;
        const short val = (short)f2bf_(acc[i][j][r] * inv);
        const int kb = col >> 5;
        const int lane2 = (row & 15) + 16 * ((col >> 3) & 3);
        Pa[((kb * 4 + i) * 64 + lane2) * 8 + (col & 7)] = val;
      }
    }
  __syncthreads();
  f32x4 accO[4];
#pragma unroll
  for (int nb = 0; nb < 4; ++nb) accO[nb] = (f32x4){0.f, 0.f, 0.f, 0.f};
  for (int kb = 0; kb < 8; ++kb) {
    bf8 ap = *(const bf8*)&Pa[((kb * 4 + w) * 64 + lane) * 8];
#pragma unroll
    for (int nb = 0; nb < 4; ++nb) {
      bf8 bfr = *(const bf8*)&w2p[(size_t)(nb * 16 + c) * 256 + kb * 32 + qd * 8];
      accO[nb] = __builtin_amdgcn_mfma_f32_16x16x32_bf16(ap, bfr, accO[nb], 0, 0, 0);
    }
  }
  // conv residual via banded MFMA: out += Band[64x96] @ Vwin[96x64]
  {
    bf8 ba[3];
    const int rl = w * 16 + (lane & 15);
#pragma unroll
    for (int kb = 0; kb < 3; ++kb) {
#pragma unroll
      for (int e = 0; e < 8; ++e) {
        const int kk = kb * 32 + qd * 8 + e;
        const int t = kk - rl;
        const int s = r0 - 16 + kk;
        const float bv = (t >= 0 && t < 33 && s >= 0 && s < 4096) ? cwS[t] : 0.f;
        ba[kb][e] = (short)f2bf_(bv);
      }
    }
#pragma unroll
    for (int kb = 0; kb < 3; ++kb) {
      int s0 = r0 - 16 + kb * 32 + qd * 8;
      s0 = s0 < 0 ? 0 : (s0 > 4088 ? 4088 : s0);
#pragma unroll
      for (int nb = 0; nb < 4; ++nb) {
        bf8 bv = *(const bf8*)&vp[(size_t)(nb * 16 + c) * 4096 + s0];
        accO[nb] = __builtin_amdgcn_mfma_f32_16x16x32_bf16(ba[kb], bv, accO[nb], 0, 0, 0);
      }
    }
  }
  short* ohp = (short*)ohb16 + (size_t)bh * QKV_STRIDE;
#pragma unroll
  for (int nb = 0; nb < 4; ++nb)
#pragma unroll
    for (int r = 0; r < 4; ++r) {
      const int row = r0 + w * 16 + qd * 4 + r;
      ohp[(size_t)row * 64 + nb * 16 + c] = (short)f2bf_(accO[nb][r]);
    }
}

// ------- out = concat_heads(oh_bf16) @ w_out + b_out (MFMA) -----------------
// 1-D grid, bn fastest: 4 consecutive blocks share one oh-tile (L2 reuse).
__global__ __launch_bounds__(256) void gemm_out_mfma(const short* __restrict__ ohb16,
                                                     const short* __restrict__ wT,
                                                     const float* __restrict__ bias,
                                                     float* __restrict__ out) {
  __shared__ short As[4096];
  __shared__ short Bs[4096];
  const int tid = threadIdx.x;
  const int lane = tid & 63, w = tid >> 6;
  const int wr = w >> 1, wc = w & 1;
  const int bn = blockIdx.x & 3, bm = blockIdx.x >> 2;
  const int gm0 = bm * 128, gn0 = bn * 128;
  const int mA0 = (tid >> 6) * 16 + (tid & 15), kA0 = ((tid >> 4) & 3) * 8;
  const int s1 = tid + 256;
  const int mA1 = (s1 >> 6) * 16 + (s1 & 15), kA1 = ((s1 >> 4) & 3) * 8;
  const int b0r = (gm0 + mA0) >> 12, seq0 = (gm0 + mA0) & 4095;
  const int b1r = (gm0 + mA1) >> 12, seq1 = (gm0 + mA1) & 4095;
  f32x4 acc[4][4];
#pragma unroll
  for (int i = 0; i < 4; ++i)
#pragma unroll
    for (int j = 0; j < 4; ++j) acc[i][j] = (f32x4){0.f, 0.f, 0.f, 0.f};
  for (int kt = 0; kt < 16; ++kt) {
    const int k0 = kt * 32;
    const int ka = k0 + kA0, kb = k0 + kA1;
    bf8 aa0 = *(const bf8*)&ohb16[(size_t)(b0r * 8 + (ka >> 6)) * QKV_STRIDE + seq0 * 64 + (ka & 63)];
    bf8 aa1 = *(const bf8*)&ohb16[(size_t)(b1r * 8 + (kb >> 6)) * QKV_STRIDE + seq1 * 64 + (kb & 63)];
    bf8 bb0 = *(const bf8*)&wT[(size_t)(gn0 + mA0) * 512 + ka];
    bf8 bb1 = *(const bf8*)&wT[(size_t)(gn0 + mA1) * 512 + kb];
    __syncthreads();
    *(bf8*)&As[tid * 8] = aa0;
    *(bf8*)&As[s1 * 8] = aa1;
    *(bf8*)&Bs[tid * 8] = bb0;
    *(bf8*)&Bs[s1 * 8] = bb1;
    __syncthreads();
    bf8 af[4], bfr[4];
#pragma unroll
    for (int i = 0; i < 4; ++i) {
      af[i] = *(const bf8*)&As[((wr * 4 + i) * 64 + lane) * 8];
      bfr[i] = *(const bf8*)&Bs[((wc * 4 + i) * 64 + lane) * 8];
    }
#pragma unroll
    for (int i = 0; i < 4; ++i)
#pragma unroll
      for (int j = 0; j < 4; ++j)
        acc[i][j] = __builtin_amdgcn_mfma_f32_16x16x32_bf16(af[i], bfr[j], acc[i][j], 0, 0, 0);
  }
  const int qd = lane >> 4, c = lane & 15;
#pragma unroll
  for (int i = 0; i < 4; ++i)
#pragma unroll
    for (int j = 0; j < 4; ++j) {
      const int col = gn0 + wc * 64 + j * 16 + c;
      const float bval = bias[col];
#pragma unroll
      for (int r = 0; r < 4; ++r) {
        const int row = gm0 + wr * 64 + i * 16 + qd * 4 + r;
        out[(size_t)row * 512 + col] = acc[i][j][r] + bval;
      }
    }
}

// ---------------------------------------------------------------------------
extern "C" void kernel_launch(void* const* d_in, const int* in_sizes, int n_in,
                              void* d_out, int out_size, void* d_ws, size_t ws_size,
                              hipStream_t stream) {
  const float* x    = (const float*)d_in[0];
  const float* wqkv = (const float*)d_in[1];
  const float* wout = (const float*)d_in[2];
  const float* bout = (const float*)d_in[3];
  const float* cw   = (const float*)d_in[4];
  float* out = (float*)d_out;

  float* w = (float*)d_ws;
  short* qb16   = (short*)(w);              // [32,4096,64] bf16
  short* kb16   = (short*)(w + 4194304);
  short* vT16   = (short*)(w + 8388608);    // [32,64,4096] bf16
  short* ohb16  = (short*)(w + 12582912);
  float* ql     = w + 16777216;             // [32,256,64] fp32
  float* kl     = w + 17301504;
  short* klb16  = (short*)(w + 17825792);
  float* x2     = w + 18087936;             // [32,256,256] fp32
  float* z0     = w + 20185088;
  float* z0t    = w + 22282240;
  float* z1     = w + 24379392;
  float* z1t    = w + 26476544;
  float* xz     = w + 28573696;
  float* xzt    = w + 30670848;
  float* u1t    = w + 32768000;
  float* u2t    = w + 34865152;
  float* av     = w + 36962304;             // [32,256,64] fp32
  short* w2tb16 = (short*)(w + 37486592);
  float* scal   = w + 37748736;             // [2]
  short* wqkvT  = (short*)(w + 37748800);
  short* woutT  = (short*)(w + 38142016);
  // aliases valid only AFTER the pinv loop (z1/z1t dead; final z in z0):
  float* opart = z1;                        // [4,32,256,64]
  float* mpart = z1t;                       // [4,32,256]
  float* lpart = z1t + 32768;               // [4,32,256]

  zero_scal<<<1, 64, 0, stream>>>(scal);
  transpose_bf16<<<dim3(48, 16), 256, 0, stream>>>(wqkv, wqkvT, 512, 1536);
  transpose_bf16<<<dim3(16, 16), 256, 0, stream>>>(wout, woutT, 512, 512);
  gemm_qkv_mfma<<<1536, 256, 0, stream>>>(x, wqkvT, qb16, kb16, vT16);
  lmk_mean<<<2048, 256, 0, stream>>>(qb16, kb16, ql, kl, klb16);
  sim2_softmax<<<512, 256, 0, stream>>>(ql, kl, x2);
  colrow_max<<<32, 256, 0, stream>>>(x2, scal);
  tscale2<<<8192, 256, 0, stream>>>(x2, scal, z0, z0t);

  float *zc = z0, *zct = z0t, *zn = z1, *znt = z1t;
  for (int it = 0; it < 6; ++it) {
    pinv_mfma<<<512, 256, 0, stream>>>(x2, zct, x2, xz, xzt, 0.f, 1.f, 1, 1);
    pinv_mfma<<<512, 256, 0, stream>>>(xz, xzt, xz, u1t, u1t, 7.f, -1.f, 0, 1);
    pinv_mfma<<<512, 256, 0, stream>>>(xz, u1t, xz, u2t, u2t, 15.f, -1.f, 0, 1);
    pinv_mfma<<<512, 256, 0, stream>>>(zc, u2t, zc, zn, znt, 3.25f, -0.25f, 1, 1);
    float* t;
    t = zc; zc = zn; zn = t;
    t = zct; zct = znt; znt = t;
  }
  // zc == z0 here; z1/z1t dead -> opart/mpart/lpart aliases live.

  attn3_flash<<<dim3(4, 4, 32), 256, 0, stream>>>(ql, kb16, vT16, opart, mpart, lpart);
  attn3_merge<<<2048, 256, 0, stream>>>(opart, mpart, lpart, av);
  zav_gemm_t<<<dim3(32, 4), 256, 0, stream>>>(zc, av, w2tb16);
  attn1_conv_mfma<<<dim3(64, 32), 256, 0, stream>>>(qb16, klb16, w2tb16, vT16, cw, ohb16);
  gemm_out_mfma<<<512, 256, 0, stream>>>(ohb16, woutT, bout, out);
}